// Round 5
// baseline (155.131 us; speedup 1.0000x reference)
//
#include <hip/hip_runtime.h>
#include <math.h>

#define G   50
#define T   24
#define B   128
#define NLP (B * T)
#define SZ  (B * G * T)   // 153600 elements per (B,G,T) output

typedef float v2f __attribute__((ext_vector_type(2)));

// d_out layout (floats, concatenated in return order):
//   [0,      SZ)        P_DA   (B,G,T)
//   [SZ,     2SZ)       R_up
//   [2SZ,    3SZ)       R_dn
//   [3SZ,    3SZ+B)     obj    (B,)   <- memset(0) + atomicAdd
//   [3SZ+B,  4SZ+B)     Cost_DA

// ---- guaranteed packed fp32 (VOP3P) helpers -------------------------------
__device__ __forceinline__ v2f pk_add(v2f a, v2f b) {
    v2f d; asm("v_pk_add_f32 %0, %1, %2" : "=v"(d) : "v"(a), "v"(b)); return d;
}
__device__ __forceinline__ v2f pk_sub(v2f a, v2f b) {  // a - b
    v2f d; asm("v_pk_add_f32 %0, %1, %2 neg_lo:[0,1] neg_hi:[0,1]"
               : "=v"(d) : "v"(a), "v"(b)); return d;
}
__device__ __forceinline__ v2f pk_fma(v2f a, v2f b, v2f c) {  // a*b + c
    v2f d; asm("v_pk_fma_f32 %0, %1, %2, %3" : "=v"(d) : "v"(a), "v"(b), "v"(c));
    return d;
}
__device__ __forceinline__ v2f pk_fms(v2f a, v2f b, v2f c) {  // a*b - c
    v2f d; asm("v_pk_fma_f32 %0, %1, %2, %3 neg_lo:[0,0,1] neg_hi:[0,0,1]"
               : "=v"(d) : "v"(a), "v"(b), "v"(c)); return d;
}
__device__ __forceinline__ v2f vmax0(v2f v) {       // 2x v_max_f32 (no pk max)
    v2f z = {0.f, 0.f};
    return __builtin_elementwise_max(v, z);
}

// DPP helper: old=0 (identity for add) + bound_ctrl -> fusable v_add_f32_dpp
template <int CTRL>
__device__ __forceinline__ float dpp_mov(float x) {
    int r = __builtin_amdgcn_update_dpp(0, __float_as_int(x), CTRL, 0xf, 0xf, true);
    return __int_as_float(r);
}

// All-reduce 3 values within each 16-lane ROW (pure DPP, chains interleaved).
__device__ __forceinline__ void row_sum3(float& a, float& b, float& c) {
    a += dpp_mov<0x121>(a); b += dpp_mov<0x121>(b); c += dpp_mov<0x121>(c); // ror:1
    a += dpp_mov<0x122>(a); b += dpp_mov<0x122>(b); c += dpp_mov<0x122>(c); // ror:2
    a += dpp_mov<0x124>(a); b += dpp_mov<0x124>(b); c += dpp_mov<0x124>(c); // ror:4
    a += dpp_mov<0x128>(a); b += dpp_mov<0x128>(b); c += dpp_mov<0x128>(c); // ror:8
}
__device__ __forceinline__ float row_sum1(float a) {
    a += dpp_mov<0x121>(a);
    a += dpp_mov<0x122>(a);
    a += dpp_mov<0x124>(a);
    a += dpp_mov<0x128>(a);
    return a;
}

// One wave per block; row r = lane>>4 (16 lanes) solves LP (4*blockIdx + r).
// Each lane owns generators {lh, lh+16} (v2f A) and {lh+32, lh+48} (v2f B;
// B.y valid iff lh<2). 50 gens total, sentinel cost clamps invalid slots.
__global__ __launch_bounds__(64)
void pdhg_lp_kernel(const float* __restrict__ forecast,
                    const float* __restrict__ pmin,
                    const float* __restrict__ pmax,
                    const float* __restrict__ bcost,
                    const float* __restrict__ ccost,
                    const int*   __restrict__ n_iters_p,
                    float* __restrict__ out,
                    float tau)
{
    const int lane = threadIdx.x;         // 0..63
    const int lh   = lane & 15;           // lane within row
    const int row  = lane >> 4;           // LP slot within wave
    const int lp   = blockIdx.x * 4 + row;
    const int b    = lp / T;
    const int t    = lp - b * T;
    const int n_iters = n_iters_p[0];

    const int  gA0 = lh,      gA1 = lh + 16;   // always < 50
    const int  gB0 = lh + 32;                  // always < 50
    const int  gB1 = lh + 48;                  // valid iff lh < 2
    const bool vB1 = (lh < 2);

    v2f bjA  = { bcost[gA0], bcost[gA1] };
    v2f bjB  = { bcost[gB0], vB1 ? bcost[gB1] : 0.f };
    v2f cjA  = { ccost[gA0], ccost[gA1] };
    v2f cjB  = { ccost[gB0], vB1 ? ccost[gB1] : 0.f };
    v2f pmxA = { pmax[gA0],  pmax[gA1] };
    v2f pmxB = { pmax[gB0],  vB1 ? pmax[gB1] : 0.f };
    v2f pmnA = { pmin[gA0],  pmin[gA1] };
    v2f pmnB = { pmin[gB0],  vB1 ? pmin[gB1] : 0.f };
    const float f = forecast[lp];         // uniform within each row

    const float ts  = tau * tau;          // sigma == tau
    const float BIG = 1e30f;              // sentinel: clamps invalid slot to 0

    const v2f tsv  = { ts, ts };
    const v2f ntsv = { -ts, -ts };
    const v2f twov = { 2.f, 2.f };

    v2f tcPA  = tau * bjA;
    v2f tcPB  = tau * bjB;           if (!vB1) tcPB.y  = BIG;
    v2f tcRuA = (tau * 0.05f) * bjA;
    v2f tcRuB = (tau * 0.05f) * bjB; if (!vB1) tcRuB.y = BIG;
    v2f tcRdA = (tau * 0.02f) * bjA;
    v2f tcRdB = (tau * 0.02f) * bjB; if (!vB1) tcRdB.y = BIG;
    v2f tspmxA = ts * pmxA, tspmxB = ts * pmxB;
    v2f tspmnA = ts * pmnA, tspmnB = ts * pmnB;
    const float tsf   = ts * f;
    const float tsreq = ts * 0.02f * f;   // REQ_UP_RATIO == REQ_DN_RATIO

    v2f PA = {0,0}, PB = {0,0}, RuA = {0,0}, RuB = {0,0}, RdA = {0,0}, RdB = {0,0};
    v2f z1A = {0,0}, z1B = {0,0}, z2A = {0,0}, z2B = {0,0};
    v2f z3A = {0,0}, z3B = {0,0}, z4A = {0,0}, z4B = {0,0};   // scaled duals tau*y
    float z0 = 0.f, zru = 0.f, zrd = 0.f;                     // row-uniform

    for (int it = 0; it < n_iters; ++it) {
        const v2f z0v  = { z0,  z0  };
        const v2f zruv = { zru, zru };
        const v2f zrdv = { zrd, zrd };

        // ---- x-update: x_new = max(x - (tau*c + tau*K^T y), 0) ----
        v2f gPA = pk_add(pk_add(pk_sub(z1A, z2A), pk_sub(z3A, z4A)), z0v);
        v2f gPB = pk_add(pk_add(pk_sub(z1B, z2B), pk_sub(z3B, z4B)), z0v);
        v2f PnA = vmax0(pk_sub(PA, pk_add(tcPA, gPA)));
        v2f PnB = vmax0(pk_sub(PB, pk_add(tcPB, gPB)));
        v2f RunA = vmax0(pk_sub(pk_add(RuA, zruv), pk_add(z1A, tcRuA)));
        v2f RunB = vmax0(pk_sub(pk_add(RuB, zruv), pk_add(z1B, tcRuB)));
        v2f RdnA = vmax0(pk_sub(pk_add(RdA, zrdv), pk_add(z2A, tcRdA)));
        v2f RdnB = vmax0(pk_sub(pk_add(RdB, zrdv), pk_add(z2B, tcRdB)));

        // overrelaxation: x_bar = 2*x_new - x_old  (pk_fms: 2*xn - x)
        v2f PbA  = pk_fms(PnA,  twov, PA);
        v2f PbB  = pk_fms(PnB,  twov, PB);
        v2f RubA = pk_fms(RunA, twov, RuA);
        v2f RubB = pk_fms(RunB, twov, RuB);
        v2f RdbA = pk_fms(RdnA, twov, RdA);
        v2f RdbB = pk_fms(RdnB, twov, RdB);
        PA = PnA; PB = PnB; RuA = RunA; RuB = RunB; RdA = RdnA; RdB = RdnB;

        // ---- row-local sums over generators (pure DPP, no LDS) ----
        v2f tP = pk_add(PbA, PbB), tRu = pk_add(RubA, RubB), tRd = pk_add(RdbA, RdbB);
        float sP  = tP.x  + tP.y;
        float sRu = tRu.x + tRu.y;
        float sRd = tRd.x + tRd.y;
        row_sum3(sP, sRu, sRd);

        // ---- z-update: z += tau*sigma*(K x_bar - q), clamp ineq rows ----
        z0 = fmaf(ts, sP, z0 - tsf);                               // equality row
        z1A = vmax0(pk_fma(tsv, pk_add(PbA, RubA), pk_sub(z1A, tspmxA)));
        z1B = vmax0(pk_fma(tsv, pk_add(PbB, RubB), pk_sub(z1B, tspmxB)));
        z2A = vmax0(pk_fma(tsv, pk_sub(RdbA, PbA), pk_add(z2A, tspmnA)));
        z2B = vmax0(pk_fma(tsv, pk_sub(RdbB, PbB), pk_add(z2B, tspmnB)));
        z3A = vmax0(pk_fma(tsv,  PbA, pk_sub(z3A, tspmxA)));
        z3B = vmax0(pk_fma(tsv,  PbB, pk_sub(z3B, tspmxB)));
        z4A = vmax0(pk_fma(ntsv, PbA, pk_add(z4A, tspmnA)));
        z4B = vmax0(pk_fma(ntsv, PbB, pk_add(z4B, tspmnB)));
        zru = fmaxf(fmaf(-ts, sRu, zru + tsreq), 0.f);             // -sum Ru <= -req
        zrd = fmaxf(fmaf(-ts, sRd, zrd + tsreq), 0.f);             // -sum Rd <= -req
    }

    const v2f costA = bjA * PA + cjA;
    const v2f costB = bjB * PB + cjB;
    {
        const int bgt = b * (G * T) + t;
        const int a0 = bgt + gA0 * T, a1 = bgt + gA1 * T, b0 = bgt + gB0 * T;
        out[a0] = PA.x;  out[SZ + a0] = RuA.x;  out[2*SZ + a0] = RdA.x;  out[3*SZ + B + a0] = costA.x;
        out[a1] = PA.y;  out[SZ + a1] = RuA.y;  out[2*SZ + a1] = RdA.y;  out[3*SZ + B + a1] = costA.y;
        out[b0] = PB.x;  out[SZ + b0] = RuB.x;  out[2*SZ + b0] = RdB.x;  out[3*SZ + B + b0] = costB.x;
        if (vB1) {
            const int b1 = bgt + gB1 * T;
            out[b1] = PB.y;  out[SZ + b1] = RuB.y;  out[2*SZ + b1] = RdB.y;  out[3*SZ + B + b1] = costB.y;
        }
    }

    // obj[b] += sum_g cost + 0.05*b*Ru + 0.02*b*Rd  (region pre-zeroed on stream)
    {
        v2f lo = costA + (0.05f * bjA) * RuA + (0.02f * bjA) * RdA
               + costB + (0.05f * bjB) * RuB + (0.02f * bjB) * RdB;
        float tot = row_sum1(lo.x + lo.y);
        if (lh == 0) atomicAdd(&out[3 * SZ + b], tot);
    }
}

extern "C" void kernel_launch(void* const* d_in, const int* in_sizes, int n_in,
                              void* d_out, int out_size, void* d_ws, size_t ws_size,
                              hipStream_t stream) {
    const float* forecast = (const float*)d_in[0];
    const float* pmin_p   = (const float*)d_in[1];
    const float* pmax_p   = (const float*)d_in[2];
    const float* b_p      = (const float*)d_in[3];
    const float* c_p      = (const float*)d_in[4];
    const int*   niter_p  = (const int*)  d_in[5];
    float* out = (float*)d_out;

    // ||K||_2 analytic for this fixed 0/±1 structure (G=50):
    // K^T K = [[4I+J, I, -I],[I, I+J, 0],[-I, 0, I+J]]; largest eig on the
    // ones-subspace is (105+sqrt(17))/2  ->  L = sqrt((105+sqrt(17))/2)
    const double L = sqrt((105.0 + sqrt(17.0)) * 0.5);
    const float tau = (float)(0.9 / L);   // sigma == tau

    // zero the obj accumulators (d_out is poisoned 0xAA before every launch)
    hipMemsetAsync(out + 3 * SZ, 0, B * sizeof(float), stream);

    pdhg_lp_kernel<<<NLP / 4, 64, 0, stream>>>(forecast, pmin_p, pmax_p,
                                               b_p, c_p, niter_p, out, tau);
}

// Round 6
// 135.988 us; speedup vs baseline: 1.1408x; 1.1408x over previous
//
#include <hip/hip_runtime.h>
#include <math.h>

#define G   50
#define T   24
#define B   128
#define NLP (B * T)
#define SZ  (B * G * T)   // 153600 elements per (B,G,T) output

typedef float v2f __attribute__((ext_vector_type(2)));

// d_out layout (floats, concatenated in return order):
//   [0,      SZ)        P_DA   (B,G,T)
//   [SZ,     2SZ)       R_up
//   [2SZ,    3SZ)       R_dn
//   [3SZ,    3SZ+B)     obj    (B,)
//   [3SZ+B,  4SZ+B)     Cost_DA

__device__ __forceinline__ v2f vmax0(v2f v) {
    v2f z = {0.f, 0.f};
    return __builtin_elementwise_max(v, z);
}

// DPP helper (outside the hot loop): row_ror rotate within 16-lane rows.
template <int CTRL>
__device__ __forceinline__ float dpp_mov(float x) {
    int r = __builtin_amdgcn_update_dpp(0, __float_as_int(x), CTRL, 0xf, 0xf, true);
    return __int_as_float(r);
}

// All-reduce 3 values within each 16-lane ROW — guaranteed single-instruction
// fused v_add_f32_dpp, 12 instructions total, chains interleaved so each
// register has >=2 intervening instructions between write and DPP read
// (2-wait-state hazard). s_nop 1 guards against the compiler-emitted producer
// immediately preceding the block.
__device__ __forceinline__ void row_sum3(float& a, float& b, float& c) {
    asm("s_nop 1\n\t"
        "v_add_f32_dpp %0, %0, %0 row_ror:1 row_mask:0xf bank_mask:0xf\n\t"
        "v_add_f32_dpp %1, %1, %1 row_ror:1 row_mask:0xf bank_mask:0xf\n\t"
        "v_add_f32_dpp %2, %2, %2 row_ror:1 row_mask:0xf bank_mask:0xf\n\t"
        "v_add_f32_dpp %0, %0, %0 row_ror:2 row_mask:0xf bank_mask:0xf\n\t"
        "v_add_f32_dpp %1, %1, %1 row_ror:2 row_mask:0xf bank_mask:0xf\n\t"
        "v_add_f32_dpp %2, %2, %2 row_ror:2 row_mask:0xf bank_mask:0xf\n\t"
        "v_add_f32_dpp %0, %0, %0 row_ror:4 row_mask:0xf bank_mask:0xf\n\t"
        "v_add_f32_dpp %1, %1, %1 row_ror:4 row_mask:0xf bank_mask:0xf\n\t"
        "v_add_f32_dpp %2, %2, %2 row_ror:4 row_mask:0xf bank_mask:0xf\n\t"
        "v_add_f32_dpp %0, %0, %0 row_ror:8 row_mask:0xf bank_mask:0xf\n\t"
        "v_add_f32_dpp %1, %1, %1 row_ror:8 row_mask:0xf bank_mask:0xf\n\t"
        "v_add_f32_dpp %2, %2, %2 row_ror:8 row_mask:0xf bank_mask:0xf"
        : "+v"(a), "+v"(b), "+v"(c));
}

__device__ __forceinline__ float row_sum1(float a) {
    a += dpp_mov<0x121>(a);
    a += dpp_mov<0x122>(a);
    a += dpp_mov<0x124>(a);
    a += dpp_mov<0x128>(a);
    return a;
}

// One wave per block; row r = lane>>4 (16 lanes) solves LP (4*blockIdx + r).
// Each lane owns generators {lh, lh+16} (v2f A) and {lh+32, lh+48} (v2f B;
// B.y valid iff lh<2). 50 gens total, sentinel cost clamps invalid slots.
__global__ __launch_bounds__(64)
void pdhg_lp_kernel(const float* __restrict__ forecast,
                    const float* __restrict__ pmin,
                    const float* __restrict__ pmax,
                    const float* __restrict__ bcost,
                    const float* __restrict__ ccost,
                    const int*   __restrict__ n_iters_p,
                    float* __restrict__ out,
                    float* __restrict__ ws_partial,   // NLP floats (or null)
                    float tau)
{
    const int lane = threadIdx.x;         // 0..63
    const int lh   = lane & 15;           // lane within row
    const int row  = lane >> 4;           // LP slot within wave
    const int lp   = blockIdx.x * 4 + row;
    const int b    = lp / T;
    const int t    = lp - b * T;
    const int n_iters = n_iters_p[0];

    const int  gA0 = lh,      gA1 = lh + 16;   // always < 50
    const int  gB0 = lh + 32;                  // always < 50
    const int  gB1 = lh + 48;                  // valid iff lh < 2
    const bool vB1 = (lh < 2);

    v2f bjA  = { bcost[gA0], bcost[gA1] };
    v2f bjB  = { bcost[gB0], vB1 ? bcost[gB1] : 0.f };
    v2f cjA  = { ccost[gA0], ccost[gA1] };
    v2f cjB  = { ccost[gB0], vB1 ? ccost[gB1] : 0.f };
    v2f pmxA = { pmax[gA0],  pmax[gA1] };
    v2f pmxB = { pmax[gB0],  vB1 ? pmax[gB1] : 0.f };
    v2f pmnA = { pmin[gA0],  pmin[gA1] };
    v2f pmnB = { pmin[gB0],  vB1 ? pmin[gB1] : 0.f };
    const float f = forecast[lp];         // uniform within each row

    const float ts  = tau * tau;          // sigma == tau
    const float BIG = 1e30f;              // sentinel: clamps invalid slot to 0

    v2f tcPA  = tau * bjA;
    v2f tcPB  = tau * bjB;           if (!vB1) tcPB.y  = BIG;
    v2f tcRuA = (tau * 0.05f) * bjA;
    v2f tcRuB = (tau * 0.05f) * bjB; if (!vB1) tcRuB.y = BIG;
    v2f tcRdA = (tau * 0.02f) * bjA;
    v2f tcRdB = (tau * 0.02f) * bjB; if (!vB1) tcRdB.y = BIG;
    v2f tspmxA = ts * pmxA, tspmxB = ts * pmxB;
    v2f tspmnA = ts * pmnA, tspmnB = ts * pmnB;
    const float tsf   = ts * f;
    const float tsreq = ts * 0.02f * f;   // REQ_UP_RATIO == REQ_DN_RATIO

    v2f PA = {0,0}, PB = {0,0}, RuA = {0,0}, RuB = {0,0}, RdA = {0,0}, RdB = {0,0};
    v2f z1A = {0,0}, z1B = {0,0}, z2A = {0,0}, z2B = {0,0};
    v2f z3A = {0,0}, z3B = {0,0}, z4A = {0,0}, z4B = {0,0};   // scaled duals tau*y
    float z0 = 0.f, zru = 0.f, zrd = 0.f;                     // row-uniform

    for (int it = 0; it < n_iters; ++it) {
        // ---- x-update: x_new = max(x - (tau*c + tau*K^T y), 0) ----
        v2f z0v = { z0, z0 };
        v2f zruv = { zru, zru };
        v2f zrdv = { zrd, zrd };
        v2f gPA = (z1A - z2A) + (z3A - z4A) + z0v;
        v2f gPB = (z1B - z2B) + (z3B - z4B) + z0v;
        v2f PnA = vmax0(PA - tcPA - gPA);
        v2f PnB = vmax0(PB - tcPB - gPB);
        v2f RunA = vmax0(RuA - tcRuA - z1A + zruv);
        v2f RunB = vmax0(RuB - tcRuB - z1B + zruv);
        v2f RdnA = vmax0(RdA - tcRdA - z2A + zrdv);
        v2f RdnB = vmax0(RdB - tcRdB - z2B + zrdv);

        // overrelaxation: x_bar = 2*x_new - x_old
        v2f PbA  = 2.f * PnA  - PA,  PbB  = 2.f * PnB  - PB;
        v2f RubA = 2.f * RunA - RuA, RubB = 2.f * RunB - RuB;
        v2f RdbA = 2.f * RdnA - RdA, RdbB = 2.f * RdnB - RdB;
        PA = PnA; PB = PnB; RuA = RunA; RuB = RunB; RdA = RdnA; RdB = RdnB;

        // ---- row-local sums over generators (fused DPP adds, no LDS) ----
        v2f tP = PbA + PbB, tRu = RubA + RubB, tRd = RdbA + RdbB;
        float sP  = tP.x  + tP.y;
        float sRu = tRu.x + tRu.y;
        float sRd = tRd.x + tRd.y;
        row_sum3(sP, sRu, sRd);

        // ---- z-update: z += tau*sigma*(K x_bar - q), clamp ineq rows ----
        z0  = z0 + ts * sP - tsf;                             // equality row
        z1A = vmax0(z1A + ts * (PbA + RubA) - tspmxA);        // P+Ru <= pmax
        z1B = vmax0(z1B + ts * (PbB + RubB) - tspmxB);
        z2A = vmax0(z2A + ts * (RdbA - PbA) + tspmnA);        // -P+Rd <= -pmin
        z2B = vmax0(z2B + ts * (RdbB - PbB) + tspmnB);
        z3A = vmax0(z3A + ts * PbA - tspmxA);                 // P <= pmax
        z3B = vmax0(z3B + ts * PbB - tspmxB);
        z4A = vmax0(z4A - ts * PbA + tspmnA);                 // -P <= -pmin
        z4B = vmax0(z4B - ts * PbB + tspmnB);
        zru = fmaxf(zru + tsreq - ts * sRu, 0.f);             // -sum Ru <= -req
        zrd = fmaxf(zrd + tsreq - ts * sRd, 0.f);             // -sum Rd <= -req
    }

    const v2f costA = bjA * PA + cjA;
    const v2f costB = bjB * PB + cjB;
    {
        const int bgt = b * (G * T) + t;
        const int a0 = bgt + gA0 * T, a1 = bgt + gA1 * T, b0 = bgt + gB0 * T;
        out[a0] = PA.x;  out[SZ + a0] = RuA.x;  out[2*SZ + a0] = RdA.x;  out[3*SZ + B + a0] = costA.x;
        out[a1] = PA.y;  out[SZ + a1] = RuA.y;  out[2*SZ + a1] = RdA.y;  out[3*SZ + B + a1] = costA.y;
        out[b0] = PB.x;  out[SZ + b0] = RuB.x;  out[2*SZ + b0] = RdB.x;  out[3*SZ + B + b0] = costB.x;
        if (vB1) {
            const int b1 = bgt + gB1 * T;
            out[b1] = PB.y;  out[SZ + b1] = RuB.y;  out[2*SZ + b1] = RdB.y;  out[3*SZ + B + b1] = costB.y;
        }
    }

    if (ws_partial) {
        // per-(b,t) objective partial: sum_g cost + 0.05*b*Ru + 0.02*b*Rd
        v2f lo = costA + (0.05f * bjA) * RuA + (0.02f * bjA) * RdA
               + costB + (0.05f * bjB) * RuB + (0.02f * bjB) * RdB;
        float tot = row_sum1(lo.x + lo.y);
        if (lh == 0) ws_partial[lp] = tot;
    }
}

// obj[b] = sum_t ws_partial[b*T + t]   (deterministic, tiny)
__global__ __launch_bounds__(64)
void obj_final_kernel(const float* __restrict__ ws_partial, float* __restrict__ out)
{
    const int b = blockIdx.x * 64 + threadIdx.x;
    if (b < B) {
        float s = 0.f;
        #pragma unroll
        for (int t = 0; t < T; ++t) s += ws_partial[b * T + t];
        out[3 * SZ + b] = s;
    }
}

// Fallback (ws too small): recompute obj from outputs, one block per b
__global__ __launch_bounds__(256)
void obj_kernel(const float* __restrict__ bcost, float* __restrict__ out)
{
    const int b = blockIdx.x;
    const float* Ru = out + SZ     + (size_t)b * (G * T);
    const float* Rd = out + 2 * SZ + (size_t)b * (G * T);
    const float* C  = out + 3 * SZ + B + (size_t)b * (G * T);

    float s = 0.f;
    for (int i = threadIdx.x; i < G * T; i += 256) {
        const int g = i / T;
        const float bg = bcost[g];
        s += C[i] + 0.05f * bg * Ru[i] + 0.02f * bg * Rd[i];
    }
    __shared__ float sm[16];
    s = row_sum1(s);                                 // 16-lane row sums
    if ((threadIdx.x & 15) == 0) sm[threadIdx.x >> 4] = s;
    __syncthreads();
    if (threadIdx.x == 0) {
        float tot = 0.f;
        #pragma unroll
        for (int i = 0; i < 16; ++i) tot += sm[i];
        out[3 * SZ + b] = tot;
    }
}

extern "C" void kernel_launch(void* const* d_in, const int* in_sizes, int n_in,
                              void* d_out, int out_size, void* d_ws, size_t ws_size,
                              hipStream_t stream) {
    const float* forecast = (const float*)d_in[0];
    const float* pmin_p   = (const float*)d_in[1];
    const float* pmax_p   = (const float*)d_in[2];
    const float* b_p      = (const float*)d_in[3];
    const float* c_p      = (const float*)d_in[4];
    const int*   niter_p  = (const int*)  d_in[5];
    float* out = (float*)d_out;

    // ||K||_2 analytic for this fixed 0/±1 structure (G=50):
    // K^T K = [[4I+J, I, -I],[I, I+J, 0],[-I, 0, I+J]]; largest eig on the
    // ones-subspace is (105+sqrt(17))/2  ->  L = sqrt((105+sqrt(17))/2)
    const double L = sqrt((105.0 + sqrt(17.0)) * 0.5);
    const float tau = (float)(0.9 / L);   // sigma == tau

    const bool use_ws = (ws_size >= (size_t)NLP * sizeof(float));
    float* wsp = use_ws ? (float*)d_ws : nullptr;

    pdhg_lp_kernel<<<NLP / 4, 64, 0, stream>>>(forecast, pmin_p, pmax_p,
                                               b_p, c_p, niter_p, out, wsp, tau);
    if (use_ws) {
        obj_final_kernel<<<(B + 63) / 64, 64, 0, stream>>>(wsp, out);
    } else {
        obj_kernel<<<B, 256, 0, stream>>>(b_p, out);
    }
}